// Round 1
// baseline (6704.216 us; speedup 1.0000x reference)
//
#include <hip/hip_runtime.h>
#include <hip/hip_fp16.h>

#define TT   2048
#define EMBD 256
#define HD   256      // H2
#define NG   1024     // 4*H2
#define NC   12
#define NEGV -10000.0f

typedef _Float16 half2v __attribute__((ext_vector_type(2)));
typedef _Float16 f16x8  __attribute__((ext_vector_type(8)));
typedef float    f32x4  __attribute__((ext_vector_type(4)));

// ---- static device scratch ----
__device__ float g_P[2 * TT * NG];   // input-GEMM preactivations, PERMUTED row order (16 MB)
__device__ float g_HS[2 * TT * HD];  // hidden states both dirs (4 MB)
__device__ float g_FE[TT * NC];      // CRF emission feats (96 KB)
__device__ uint4 g_WF[2][4][64][64]; // staged f16 A-fragments, kt=4..7 (512 KB, L2-resident)

__device__ __forceinline__ unsigned int f2h2(float a, float b) {
  half2v h; h.x = (_Float16)a; h.y = (_Float16)b;
  return __builtin_bit_cast(unsigned int, h);
}
__device__ __forceinline__ f16x8 asf16x8(uint4 v) { return __builtin_bit_cast(f16x8, v); }
__device__ __forceinline__ float fsigmoid(float x) { return 1.0f / (1.0f + __expf(-x)); }
__device__ __forceinline__ float ftanh(float x) {
  float a = fabsf(x);
  float e = __expf(-2.0f * a);
  float r = (1.0f - e) / (1.0f + e);
  return copysignf(r, x);
}

// Row permutation shared by k_input (writer) and k_rec (reader):
// unit u = w*64 + rt*4 + lg  (w: wave 0..3, rt: rowtile 0..15, lg: unit-in-tile 0..3)
// permuted row r' = w*256 + rt*16 + lg*4 + ga   (ga: gate 0..3 = i,f,g,o)

// ---------------- K1: embedding gather + input GEMM (+ both biases), f32 ----------------
__global__ __launch_bounds__(256) void k_input(
    const int* __restrict__ sent, const float* __restrict__ emb,
    const float* __restrict__ WihF, const float* __restrict__ bihF,
    const float* __restrict__ bhhF,
    const float* __restrict__ WihB, const float* __restrict__ bihB,
    const float* __restrict__ bhhB)
{
  const int d  = blockIdx.x & 1;
  const int t0 = (blockIdx.x >> 1) * 16;
  const float* Wih = d ? WihB : WihF;
  const float* bih = d ? bihB : bihF;
  const float* bhh = d ? bhhB : bhhF;
  __shared__ float xs[16][EMBD];
  for (int i = threadIdx.x; i < 16 * (EMBD / 4); i += 256) {
    const int tt = i >> 6, e4 = i & 63;
    reinterpret_cast<float4*>(xs[tt])[e4] =
        reinterpret_cast<const float4*>(emb + (size_t)sent[t0 + tt] * EMBD)[e4];
  }
  __syncthreads();
  for (int gg = 0; gg < 4; ++gg) {
    const int g = threadIdx.x + gg * 256;
    const float bias = bih[g] + bhh[g];
    float acc[16];
#pragma unroll
    for (int tt = 0; tt < 16; ++tt) acc[tt] = 0.0f;
    const float* wr = Wih + (size_t)g * EMBD;
    for (int e = 0; e < EMBD; e += 4) {
      const float4 w = *reinterpret_cast<const float4*>(wr + e);
#pragma unroll
      for (int tt = 0; tt < 16; ++tt) {
        acc[tt] += w.x * xs[tt][e] + w.y * xs[tt][e + 1]
                 + w.z * xs[tt][e + 2] + w.w * xs[tt][e + 3];
      }
    }
    // permuted write: row' = w*256 + rt*16 + lg*4 + ga
    const int u = g & 255, ga = g >> 8;
    const int rp = ((u >> 6) << 8) + (((u >> 2) & 15) << 4) + ((u & 3) << 2) + ga;
    float* Pg = g_P + ((size_t)d * TT + t0) * NG + rp;
#pragma unroll
    for (int tt = 0; tt < 16; ++tt) Pg[(size_t)tt * NG] = acc[tt] + bias;
  }
}

// ---------------- K2: BiLSTM recurrence on the MFMA pipe ----------------
// 256 threads/block (4 waves, 1 wave/SIMD), 1 block/direction.
// Per wave: 16 rowtiles of 16 permuted gate-rows (= 64 units), K=256 as 8 k-tiles.
// A-frags kt0..3 resident (AGPR), kt4..7 streamed from g_WF (L2) each step.
// B = h broadcast into all 16 MFMA columns -> every lane's D is valid.
__global__ __launch_bounds__(256, 1) void k_rec(
    const float* __restrict__ WhhF, const float* __restrict__ WhhB,
    const float* __restrict__ h0g, const float* __restrict__ c0g)
{
  __shared__ __align__(16) unsigned short h2[2][HD];   // f16 h, double buffered (1 KB)
  __shared__ __align__(16) float gates[4][64][4];      // per-wave (i,f,g,o) per unit (4 KB)

  const int d = blockIdx.x;
  const float* __restrict__ Whh = d ? WhhB : WhhF;
  const int tid  = threadIdx.x;
  const int w    = tid >> 6;
  const int lane = tid & 63;
  const int kg   = lane >> 4;        // k-group 0..3  (A: k = kt*32 + kg*8 + j)
  const int m    = lane & 15;        // A-row within 16-tile (m = lg*4 + ga)
  const int lg   = m >> 2, ga = m & 3;

  // ---- pack A fragments: f32 -> f16, kt0..3 to registers, kt4..7 to g_WF ----
  uint4 Ares[16][4];
#pragma unroll
  for (int rt = 0; rt < 16; ++rt) {
    const int orow = (ga << 8) + (w << 6) + (rt << 2) + lg;  // original Whh row
    const float* wr = Whh + (size_t)orow * HD;
#pragma unroll
    for (int kt = 0; kt < 8; ++kt) {
      const int k0 = (kt << 5) + (kg << 3);
      const float4 x0 = *reinterpret_cast<const float4*>(wr + k0);
      const float4 x1 = *reinterpret_cast<const float4*>(wr + k0 + 4);
      uint4 f;
      f.x = f2h2(x0.x, x0.y); f.y = f2h2(x0.z, x0.w);
      f.z = f2h2(x1.x, x1.y); f.w = f2h2(x1.z, x1.w);
      if (kt < 4) Ares[rt][kt] = f;
      else        g_WF[d][w][(rt << 2) + (kt - 4)][lane] = f;
    }
  }
  __threadfence();   // make g_WF stores visible before the step loop re-reads them

  if (tid < HD / 2)
    reinterpret_cast<unsigned int*>(h2[0])[tid] =
        f2h2(h0g[d * HD + 2 * tid], h0g[d * HD + 2 * tid + 1]);
  float c = c0g[d * HD + (w << 6) + lane];   // this lane's unit state
  __syncthreads();

  const float* Pbase = g_P + (size_t)d * TT * NG + (w << 8) + (lane << 2);
  const uint4* wfb = &g_WF[d][w][0][lane];

  int t = d ? (TT - 1) : 0;
  const int tstep = d ? -1 : 1;
  float4 Pc = *reinterpret_cast<const float4*>(Pbase + (size_t)t * NG);
  int p = 0;

  for (int it = 0; it < TT; ++it, t += tstep) {
    // defeat LICM: keep the staged-weight stream as per-iteration L2 loads
    asm volatile("" : "+v"(wfb));

    // B fragments: h(t-1) f16x8 slices, broadcast within 16-lane groups
    f16x8 bf[8];
#pragma unroll
    for (int kt = 0; kt < 8; ++kt)
      bf[kt] = asf16x8(*reinterpret_cast<const uint4*>(&h2[p][(kt << 5) + (kg << 3)]));

    // prefetch next-step P under the MFMA phase
    const int tn = (it + 1 < TT) ? (t + tstep) : t;
    const float4 Pn = *reinterpret_cast<const float4*>(Pbase + (size_t)tn * NG);

    uint4 sg[16][4];
#pragma unroll
    for (int rt = 0; rt < 4; ++rt) {
#pragma unroll
      for (int j = 0; j < 4; ++j) sg[rt][j] = wfb[(size_t)(((rt << 2) + j) << 6)];
    }

#pragma unroll
    for (int rt = 0; rt < 16; ++rt) {
      if (rt + 4 < 16) {   // stream 4 rowtiles ahead (~160 cyc of MFMA cover)
#pragma unroll
        for (int j = 0; j < 4; ++j)
          sg[rt + 4][j] = wfb[(size_t)((((rt + 4) << 2) + j) << 6)];
      }
      f32x4 acc = {0.f, 0.f, 0.f, 0.f};
#pragma unroll
      for (int kt = 0; kt < 4; ++kt)
        acc = __builtin_amdgcn_mfma_f32_16x16x32_f16(asf16x8(Ares[rt][kt]), bf[kt], acc, 0, 0, 0);
#pragma unroll
      for (int kt = 4; kt < 8; ++kt)
        acc = __builtin_amdgcn_mfma_f32_16x16x32_f16(asf16x8(sg[rt][kt - 4]), bf[kt], acc, 0, 0, 0);
      // D: row = kg*4 + reg -> unit rt*4+kg holds (i,f,g,o) in regs 0..3, replicated over cols
      if (m == 0)
        *reinterpret_cast<float4*>(gates[w][(rt << 2) + kg]) = __builtin_bit_cast(float4, acc);
    }

    // ---- cell update: lane <-> unit u = w*64 + lane (in-wave LDS exchange only) ----
    const float4 gv = *reinterpret_cast<const float4*>(gates[w][lane]);
    const float gi = gv.x + Pc.x;
    const float gf = gv.y + Pc.y;
    const float gz = gv.z + Pc.z;
    const float go = gv.w + Pc.w;
    c = fsigmoid(gf) * c + fsigmoid(gi) * ftanh(gz);
    const float hh = fsigmoid(go) * ftanh(c);
    g_HS[((size_t)d * TT + t) * HD + (w << 6) + lane] = hh;   // f32 for feats
    h2[p ^ 1][(w << 6) + lane] = __builtin_bit_cast(unsigned short, (_Float16)hh);
    Pc = Pn;
    p ^= 1;
    // LDS-only drain + raw barrier: do NOT vmcnt-drain the g_HS store / prefetches
    asm volatile("s_waitcnt lgkmcnt(0)" ::: "memory");
    __builtin_amdgcn_s_barrier();
    __builtin_amdgcn_sched_barrier(0);
  }
}

// ---------------- K3: feats = [hf;hb] @ Wlin^T + blin (pure f32) ----------------
__global__ __launch_bounds__(256) void k_feats(
    const float* __restrict__ Wlin, const float* __restrict__ blin)
{
  const int gid = blockIdx.x * 256 + threadIdx.x;
  if (gid >= TT * NC) return;
  const int t = gid / NC, cc = gid - t * NC;
  const float* hf = g_HS + (size_t)t * HD;
  const float* hb = g_HS + ((size_t)TT + t) * HD;
  const float* wr = Wlin + cc * 512;
  float acc = blin[cc];
  for (int j = 0; j < HD; j += 4) {
    const float4 w = *reinterpret_cast<const float4*>(wr + j);
    acc += w.x * hf[j] + w.y * hf[j + 1] + w.z * hf[j + 2] + w.w * hf[j + 3];
  }
  for (int j = 0; j < HD; j += 4) {
    const float4 w = *reinterpret_cast<const float4*>(wr + 256 + j);
    acc += w.x * hb[j] + w.y * hb[j + 1] + w.z * hb[j + 2] + w.w * hb[j + 3];
  }
  g_FE[gid] = acc;
}

// ---------------- K4: Viterbi + backtrace (single wave); f32 in/out ----------------
__global__ __launch_bounds__(64) void k_vit(
    const float* __restrict__ trans, float* __restrict__ out)
{
  const int lane = threadIdx.x;
  const bool act = lane < NC;
  __shared__ unsigned char bp[TT][NC];
  float Trow[NC];
#pragma unroll
  for (int i = 0; i < NC; ++i) Trow[i] = act ? trans[lane * NC + i] : NEGV;
  float fv[NC];
#pragma unroll
  for (int i = 0; i < NC; ++i) fv[i] = (i == 10) ? 0.0f : NEGV;  // START=10

  float f0 = act ? g_FE[lane] : 0.0f;                 // 2-deep FE prefetch
  float f1 = act ? g_FE[NC + lane] : 0.0f;
  for (int t = 0; t < TT; ++t) {
    const float feat = f0;
    f0 = f1;
    f1 = (act && t + 2 < TT) ? g_FE[(t + 2) * NC + lane] : 0.0f;
    float best = fv[0] + Trow[0]; int bi = 0;
#pragma unroll
    for (int i = 1; i < NC; ++i) {
      const float s = fv[i] + Trow[i];
      if (s > best) { best = s; bi = i; }   // strict > == jnp first-max tiebreak
    }
    if (act) bp[t][lane] = (unsigned char)bi;
    const float nf = best + feat;
#pragma unroll
    for (int i = 0; i < NC; ++i) fv[i] = __shfl(nf, i);
  }
  // terminal = fv + transitions[STOP=11] (row 11)
  const float term = act ? (fv[lane] + trans[11 * NC + lane]) : -3.0e38f;
  float tv[NC];
#pragma unroll
  for (int i = 0; i < NC; ++i) tv[i] = __shfl(term, i);
  if (lane == 0) {
    float bs = tv[0]; int bt = 0;
#pragma unroll
    for (int i = 1; i < NC; ++i) if (tv[i] > bs) { bs = tv[i]; bt = i; }
    out[0] = bs;                             // f32 path_score
    int tag = bt;
    for (int t = TT - 1; t >= 0; --t) {
      out[1 + t] = (float)tag;               // path tags as f32
      tag = bp[t][tag];
    }
  }
}

extern "C" void kernel_launch(void* const* d_in, const int* in_sizes, int n_in,
                              void* d_out, int out_size, void* d_ws, size_t ws_size,
                              hipStream_t stream) {
  const int*   sent = (const int*)d_in[0];
  const float* emb  = (const float*)d_in[1];
  const float* WihF = (const float*)d_in[2];
  const float* WhhF = (const float*)d_in[3];
  const float* bihF = (const float*)d_in[4];
  const float* bhhF = (const float*)d_in[5];
  const float* WihB = (const float*)d_in[6];
  const float* WhhB = (const float*)d_in[7];
  const float* bihB = (const float*)d_in[8];
  const float* bhhB = (const float*)d_in[9];
  const float* Wlin = (const float*)d_in[10];
  const float* blin = (const float*)d_in[11];
  const float* h0g  = (const float*)d_in[12];
  const float* c0g  = (const float*)d_in[13];
  const float* trans= (const float*)d_in[14];
  (void)d_ws; (void)ws_size; (void)in_sizes; (void)n_in; (void)out_size;

  k_input<<<dim3(2 * (TT / 16)), dim3(256), 0, stream>>>(
      sent, emb, WihF, bihF, bhhF, WihB, bihB, bhhB);

  k_rec<<<dim3(2), dim3(256), 0, stream>>>(WhhF, WhhB, h0g, c0g);

  k_feats<<<dim3((TT * NC + 255) / 256), dim3(256), 0, stream>>>(Wlin, blin);

  k_vit<<<dim3(1), dim3(64), 0, stream>>>(trans, (float*)d_out);
}

// Round 2
// 4358.367 us; speedup vs baseline: 1.5382x; 1.5382x over previous
//
#include <hip/hip_runtime.h>
#include <hip/hip_fp16.h>

#define TT   2048
#define EMBD 256
#define HD   256      // H2
#define NG   1024     // 4*H2
#define NC   12
#define NEGV -10000.0f

typedef _Float16 half2v __attribute__((ext_vector_type(2)));
typedef _Float16 f16x8  __attribute__((ext_vector_type(8)));
typedef float    f32x4  __attribute__((ext_vector_type(4)));

// ---- static device scratch ----
__device__ float g_P[2 * TT * NG];   // input-GEMM preactivations, permuted: gate ga of unit u at 4u+ga (16 MB)
__device__ float g_HS[2 * TT * HD];  // hidden states both dirs (4 MB)
__device__ float g_FE[TT * NC];      // CRF emission feats (96 KB)

__device__ __forceinline__ unsigned int f2h2(float a, float b) {
  half2v h; h.x = (_Float16)a; h.y = (_Float16)b;
  return __builtin_bit_cast(unsigned int, h);
}
__device__ __forceinline__ f16x8 asf16x8(uint4 v) { return __builtin_bit_cast(f16x8, v); }
__device__ __forceinline__ float fsigmoid(float x) { return 1.0f / (1.0f + __expf(-x)); }
__device__ __forceinline__ float ftanh(float x) {
  float a = fabsf(x);
  float e = __expf(-2.0f * a);
  float r = (1.0f - e) / (1.0f + e);
  return copysignf(r, x);
}

// Row permutation shared by k_input (writer) and k_rec (reader):
// original gate-row g = ga*256 + u  ->  permuted row r' = 4*u + ga
// (so P for unit u is one contiguous float4 = (i,f,g,o))

// ---------------- K1: embedding gather + input GEMM (+ both biases), f32 ----------------
__global__ __launch_bounds__(256) void k_input(
    const int* __restrict__ sent, const float* __restrict__ emb,
    const float* __restrict__ WihF, const float* __restrict__ bihF,
    const float* __restrict__ bhhF,
    const float* __restrict__ WihB, const float* __restrict__ bihB,
    const float* __restrict__ bhhB)
{
  const int d  = blockIdx.x & 1;
  const int t0 = (blockIdx.x >> 1) * 16;
  const float* Wih = d ? WihB : WihF;
  const float* bih = d ? bihB : bihF;
  const float* bhh = d ? bhhB : bhhF;
  __shared__ float xs[16][EMBD];
  for (int i = threadIdx.x; i < 16 * (EMBD / 4); i += 256) {
    const int tt = i >> 6, e4 = i & 63;
    reinterpret_cast<float4*>(xs[tt])[e4] =
        reinterpret_cast<const float4*>(emb + (size_t)sent[t0 + tt] * EMBD)[e4];
  }
  __syncthreads();
  for (int gg = 0; gg < 4; ++gg) {
    const int g = threadIdx.x + gg * 256;
    const float bias = bih[g] + bhh[g];
    float acc[16];
#pragma unroll
    for (int tt = 0; tt < 16; ++tt) acc[tt] = 0.0f;
    const float* wr = Wih + (size_t)g * EMBD;
    for (int e = 0; e < EMBD; e += 4) {
      const float4 w = *reinterpret_cast<const float4*>(wr + e);
#pragma unroll
      for (int tt = 0; tt < 16; ++tt) {
        acc[tt] += w.x * xs[tt][e] + w.y * xs[tt][e + 1]
                 + w.z * xs[tt][e + 2] + w.w * xs[tt][e + 3];
      }
    }
    const int u = g & 255, ga = g >> 8;
    const int rp = 4 * u + ga;            // permuted row
    float* Pg = g_P + ((size_t)d * TT + t0) * NG + rp;
#pragma unroll
    for (int tt = 0; tt < 16; ++tt) Pg[(size_t)tt * NG] = acc[tt] + bias;
  }
}

// ---------------- K2: BiLSTM recurrence — MFMA, 8 waves, LDS-streamed weight tail ----------------
// 512 threads (8 waves, 2/SIMD), 1 block/direction.
// Per wave: 8 rowtiles x 16 permuted gate-rows (= 32 units), K=256 as 8 k-tiles.
// kt0..5 resident in registers (192 VGPR), kt6..7 in LDS (128 KB), streamed each step
// at LDS BW (~2x per-CU L2 BW) instead of round-1's L2 stream.
__global__ __launch_bounds__(512, 2) void k_rec(
    const float* __restrict__ WhhF, const float* __restrict__ WhhB,
    const float* __restrict__ h0g, const float* __restrict__ c0g)
{
  __shared__ __align__(16) uint4 wlds[8][8][2][64];     // 128 KB: A-frags kt6..7
  __shared__ __align__(16) unsigned short h2[2][HD];    // 1 KB: f16 h, double buffered
  __shared__ __align__(16) float gates[256][4];         // 4 KB: (i,f,g,o) per unit

  const int d = blockIdx.x;
  const float* __restrict__ Whh = d ? WhhB : WhhF;
  const int tid  = threadIdx.x;
  const int w    = tid >> 6;
  const int lane = tid & 63;
  const int kg   = lane >> 4;        // k-group 0..3 (A/B: k = kt*32 + kg*8 + j)
  const int m    = lane & 15;        // A-row within 16-tile (m = lg*4 + ga)
  const int lg   = m >> 2, ga = m & 3;

  // ---- pack A fragments f32 -> f16: kt0..5 to registers, kt6..7 to LDS ----
  uint4 Ares[8][6];
#pragma unroll
  for (int rt = 0; rt < 8; ++rt) {
    const int orow = (ga << 8) + (w << 5) + (rt << 2) + lg;  // original Whh row
    const float* wr = Whh + (size_t)orow * HD;
#pragma unroll
    for (int kt = 0; kt < 8; ++kt) {
      const int k0 = (kt << 5) + (kg << 3);
      const float4 x0 = *reinterpret_cast<const float4*>(wr + k0);
      const float4 x1 = *reinterpret_cast<const float4*>(wr + k0 + 4);
      uint4 f;
      f.x = f2h2(x0.x, x0.y); f.y = f2h2(x0.z, x0.w);
      f.z = f2h2(x1.x, x1.y); f.w = f2h2(x1.z, x1.w);
      if (kt < 6) Ares[rt][kt] = f;
      else        wlds[w][rt][kt - 6][lane] = f;
    }
  }
  if (tid < HD / 2)
    reinterpret_cast<unsigned int*>(h2[0])[tid] =
        f2h2(h0g[d * HD + 2 * tid], h0g[d * HD + 2 * tid + 1]);
  float c = (tid < 256) ? c0g[d * HD + tid] : 0.0f;   // lane tid<256 owns unit u=tid
  __syncthreads();

  const float* Pbase = g_P + (size_t)d * TT * NG + 4 * tid;  // unit u=tid: float4 (i,f,g,o)
  int t = d ? (TT - 1) : 0;
  const int tstep = d ? -1 : 1;
  float4 Pc = {0.f, 0.f, 0.f, 0.f};
  if (tid < 256) Pc = *reinterpret_cast<const float4*>(Pbase + (size_t)t * NG);
  int p = 0;

  for (int it = 0; it < TT; ++it, t += tstep) {
    // B fragments: h(t-1) f16x8 slices, broadcast within 16-lane groups
    f16x8 bf[8];
#pragma unroll
    for (int kt = 0; kt < 8; ++kt)
      bf[kt] = asf16x8(*reinterpret_cast<const uint4*>(&h2[p][(kt << 5) + (kg << 3)]));

#pragma unroll
    for (int rt = 0; rt < 8; ++rt) {
      const uint4 sa = wlds[w][rt][0][lane];   // streamed kt6
      const uint4 sb = wlds[w][rt][1][lane];   // streamed kt7
      f32x4 acc = {0.f, 0.f, 0.f, 0.f};
#pragma unroll
      for (int kt = 0; kt < 6; ++kt)
        acc = __builtin_amdgcn_mfma_f32_16x16x32_f16(asf16x8(Ares[rt][kt]), bf[kt], acc, 0, 0, 0);
      acc = __builtin_amdgcn_mfma_f32_16x16x32_f16(asf16x8(sa), bf[6], acc, 0, 0, 0);
      acc = __builtin_amdgcn_mfma_f32_16x16x32_f16(asf16x8(sb), bf[7], acc, 0, 0, 0);
      // D: row = kg*4 + reg -> unit w*32 + rt*4 + kg holds (i,f,g,o) in regs 0..3
      if (m == 0)
        *reinterpret_cast<float4*>(gates[(w << 5) + (rt << 2) + kg]) =
            __builtin_bit_cast(float4, acc);
    }
    // barrier 1: gates ready (LDS-only drain; g_HS stores / P loads stay in flight)
    asm volatile("s_waitcnt lgkmcnt(0)" ::: "memory");
    __builtin_amdgcn_s_barrier();
    __builtin_amdgcn_sched_barrier(0);

    if (tid < 256) {   // waves 0..3: cell update, one lane per unit
      const float4 gv = *reinterpret_cast<const float4*>(gates[tid]);
      const float gi = gv.x + Pc.x;
      const float gf = gv.y + Pc.y;
      const float gz = gv.z + Pc.z;
      const float go = gv.w + Pc.w;
      c = fsigmoid(gf) * c + fsigmoid(gi) * ftanh(gz);
      const float hh = fsigmoid(go) * ftanh(c);
      g_HS[((size_t)d * TT + t) * HD + tid] = hh;          // f32 for feats
      h2[p ^ 1][tid] = __builtin_bit_cast(unsigned short, (_Float16)hh);
      // reload P for next step right after use: a full step of latency cover
      const int tn = (it + 1 < TT) ? (t + tstep) : t;
      Pc = *reinterpret_cast<const float4*>(Pbase + (size_t)tn * NG);
    }
    p ^= 1;
    // barrier 2: h2 ready for next step's B-frag reads
    asm volatile("s_waitcnt lgkmcnt(0)" ::: "memory");
    __builtin_amdgcn_s_barrier();
    __builtin_amdgcn_sched_barrier(0);
  }
}

// ---------------- K3: feats = [hf;hb] @ Wlin^T + blin (pure f32) ----------------
__global__ __launch_bounds__(256) void k_feats(
    const float* __restrict__ Wlin, const float* __restrict__ blin)
{
  const int gid = blockIdx.x * 256 + threadIdx.x;
  if (gid >= TT * NC) return;
  const int t = gid / NC, cc = gid - t * NC;
  const float* hf = g_HS + (size_t)t * HD;
  const float* hb = g_HS + ((size_t)TT + t) * HD;
  const float* wr = Wlin + cc * 512;
  float acc = blin[cc];
  for (int j = 0; j < HD; j += 4) {
    const float4 w = *reinterpret_cast<const float4*>(wr + j);
    acc += w.x * hf[j] + w.y * hf[j + 1] + w.z * hf[j + 2] + w.w * hf[j + 3];
  }
  for (int j = 0; j < HD; j += 4) {
    const float4 w = *reinterpret_cast<const float4*>(wr + 256 + j);
    acc += w.x * hb[j] + w.y * hb[j + 1] + w.z * hb[j + 2] + w.w * hb[j + 3];
  }
  g_FE[gid] = acc;
}

// ---------------- K4: Viterbi + backtrace (single wave); f32 in/out ----------------
__global__ __launch_bounds__(64) void k_vit(
    const float* __restrict__ trans, float* __restrict__ out)
{
  const int lane = threadIdx.x;
  const bool act = lane < NC;
  __shared__ unsigned char bp[TT][NC];
  float Trow[NC];
#pragma unroll
  for (int i = 0; i < NC; ++i) Trow[i] = act ? trans[lane * NC + i] : NEGV;
  float fv[NC];
#pragma unroll
  for (int i = 0; i < NC; ++i) fv[i] = (i == 10) ? 0.0f : NEGV;  // START=10

  float f0 = act ? g_FE[lane] : 0.0f;                 // 2-deep FE prefetch
  float f1 = act ? g_FE[NC + lane] : 0.0f;
  for (int t = 0; t < TT; ++t) {
    const float feat = f0;
    f0 = f1;
    f1 = (act && t + 2 < TT) ? g_FE[(t + 2) * NC + lane] : 0.0f;
    float best = fv[0] + Trow[0]; int bi = 0;
#pragma unroll
    for (int i = 1; i < NC; ++i) {
      const float s = fv[i] + Trow[i];
      if (s > best) { best = s; bi = i; }   // strict > == jnp first-max tiebreak
    }
    if (act) bp[t][lane] = (unsigned char)bi;
    const float nf = best + feat;
#pragma unroll
    for (int i = 0; i < NC; ++i) fv[i] = __shfl(nf, i);
  }
  // terminal = fv + transitions[STOP=11] (row 11)
  const float term = act ? (fv[lane] + trans[11 * NC + lane]) : -3.0e38f;
  float tv[NC];
#pragma unroll
  for (int i = 0; i < NC; ++i) tv[i] = __shfl(term, i);
  if (lane == 0) {
    float bs = tv[0]; int bt = 0;
#pragma unroll
    for (int i = 1; i < NC; ++i) if (tv[i] > bs) { bs = tv[i]; bt = i; }
    out[0] = bs;                             // f32 path_score
    int tag = bt;
    for (int t = TT - 1; t >= 0; --t) {
      out[1 + t] = (float)tag;               // path tags as f32
      tag = bp[t][tag];
    }
  }
}

extern "C" void kernel_launch(void* const* d_in, const int* in_sizes, int n_in,
                              void* d_out, int out_size, void* d_ws, size_t ws_size,
                              hipStream_t stream) {
  const int*   sent = (const int*)d_in[0];
  const float* emb  = (const float*)d_in[1];
  const float* WihF = (const float*)d_in[2];
  const float* WhhF = (const float*)d_in[3];
  const float* bihF = (const float*)d_in[4];
  const float* bhhF = (const float*)d_in[5];
  const float* WihB = (const float*)d_in[6];
  const float* WhhB = (const float*)d_in[7];
  const float* bihB = (const float*)d_in[8];
  const float* bhhB = (const float*)d_in[9];
  const float* Wlin = (const float*)d_in[10];
  const float* blin = (const float*)d_in[11];
  const float* h0g  = (const float*)d_in[12];
  const float* c0g  = (const float*)d_in[13];
  const float* trans= (const float*)d_in[14];
  (void)d_ws; (void)ws_size; (void)in_sizes; (void)n_in; (void)out_size;

  k_input<<<dim3(2 * (TT / 16)), dim3(256), 0, stream>>>(
      sent, emb, WihF, bihF, bhhF, WihB, bihB, bhhB);

  k_rec<<<dim3(2), dim3(512), 0, stream>>>(WhhF, WhhB, h0g, c0g);

  k_feats<<<dim3((TT * NC + 255) / 256), dim3(256), 0, stream>>>(Wlin, blin);

  k_vit<<<dim3(1), dim3(64), 0, stream>>>(trans, (float*)d_out);
}